// Round 2
// baseline (384.754 us; speedup 1.0000x reference)
//
#include <hip/hip_runtime.h>

typedef __bf16 bf16_t;
typedef __attribute__((ext_vector_type(4))) __bf16 bf16x4;
typedef __attribute__((ext_vector_type(8))) __bf16 bf16x8;
typedef __attribute__((ext_vector_type(4))) float floatx4;

#define LN_EPS 1e-5f

// =====================================================================
// K0: c_all[r][c] = bi[c] + bt[c]   (init for split-K atomic accumulation)
// 17408*128 floats = 557056 float4 -> 2176 blocks x 256
// =====================================================================
__global__ __launch_bounds__(256) void k0_init(
    const float* __restrict__ bi, const float* __restrict__ bt,
    float* __restrict__ c_all)
{
    int i = blockIdx.x * 256 + threadIdx.x;      // float4 index
    int c4 = i & 31;
    float4 a = ((const float4*)bi)[c4];
    float4 b = ((const float4*)bt)[c4];
    float4 v; v.x = a.x + b.x; v.y = a.y + b.y; v.z = a.z + b.z; v.w = a.w + b.w;
    ((float4*)c_all)[i] = v;
}

// =====================================================================
// K1: c_all += [img|txt] @ [Wi|Wt]^T   (split-K x4, atomicAdd epilogue)
// M=17408, N=128, K=2816. BM=64, BN=128, BK=64, K-chunk=704 (11 slabs).
// grid (272, 4); 256 thr = 4 waves (2x2 of 32x64 = 2x4 mfma 16x16x32).
// 272 blocks was 1 block/CU => 11% occupancy, latency-bound (R1 counters);
// 1088 blocks => ~4.25 blocks/CU for wave-level overlap across barriers.
// =====================================================================
#define K1_SA 72   // bf16 stride for BK=64 (+8 pad): row step 36 dw = 4 banks, 2-way (free)
#define K1_SB 72

__global__ __launch_bounds__(256) void k1_gemm(
    const float* __restrict__ qimg, const float* __restrict__ qtxt,
    const float* __restrict__ simg, const float* __restrict__ stxt,
    const float* __restrict__ Wi,   const float* __restrict__ Wt,
    float* __restrict__ c_all)
{
    __shared__ bf16_t lA[64 * K1_SA];
    __shared__ bf16_t lB[128 * K1_SB];

    const int tid  = threadIdx.x;
    const int m0   = blockIdx.x * 64;
    const int chnk = blockIdx.y;
    const bool isq = (m0 < 16384);
    const int rb   = isq ? m0 : (m0 - 16384);
    const float* Aimg = isq ? qimg : simg;
    const float* Atxt = isq ? qtxt : stxt;

    const int wid  = tid >> 6;
    const int lane = tid & 63;
    const int quad = lane >> 4;
    const int l16  = lane & 15;
    const int wr   = wid >> 1;
    const int wc   = wid & 1;

    // staging: A row = tid>>2, 4 float4 at col (tid&3)*4 + 16j  (lanes 0..3 contiguous 64B)
    const int arow = tid >> 2, acol = (tid & 3) * 4;

    floatx4 acc[2][4];
#pragma unroll
    for (int i = 0; i < 2; ++i)
#pragma unroll
        for (int j = 0; j < 4; ++j) acc[i][j] = (floatx4)0.f;

    for (int s = 0; s < 11; ++s) {
        const int k0 = chnk * 704 + s * 64;     // slab-aligned: never straddles 2048
        const float* abase; const float* bbase; size_t lda, ldb;
        if (k0 < 2048) {
            abase = Aimg + (size_t)rb * 2048 + k0; lda = 2048;
            bbase = Wi + k0;                        ldb = 2048;
        } else {
            abase = Atxt + (size_t)rb * 768 + (k0 - 2048); lda = 768;
            bbase = Wt + (k0 - 2048);                       ldb = 768;
        }
        __syncthreads();
        {   // A tile 64x64
            const float* p = abase + (size_t)arow * lda + acol;
#pragma unroll
            for (int j = 0; j < 4; ++j) {
                float4 v = *(const float4*)(p + 16 * j);
                bf16x4 pk; pk.x = (bf16_t)v.x; pk.y = (bf16_t)v.y;
                           pk.z = (bf16_t)v.z; pk.w = (bf16_t)v.w;
                *(bf16x4*)&lA[arow * K1_SA + acol + 16 * j] = pk;
            }
        }
#pragma unroll
        for (int pp = 0; pp < 2; ++pp) {   // B tile 128x64, two 64-row passes
            int brow = pp * 64 + (tid >> 2);
            const float* p = bbase + (size_t)brow * ldb + acol;
#pragma unroll
            for (int j = 0; j < 4; ++j) {
                float4 v = *(const float4*)(p + 16 * j);
                bf16x4 pk; pk.x = (bf16_t)v.x; pk.y = (bf16_t)v.y;
                           pk.z = (bf16_t)v.z; pk.w = (bf16_t)v.w;
                *(bf16x4*)&lB[brow * K1_SB + acol + 16 * j] = pk;
            }
        }
        __syncthreads();
#pragma unroll
        for (int ks = 0; ks < 2; ++ks) {
            bf16x8 af[2], bfr[4];
#pragma unroll
            for (int mt = 0; mt < 2; ++mt)
                af[mt] = *(const bf16x8*)&lA[(wr * 32 + mt * 16 + l16) * K1_SA + ks * 32 + quad * 8];
#pragma unroll
            for (int nt = 0; nt < 4; ++nt)
                bfr[nt] = *(const bf16x8*)&lB[(wc * 64 + nt * 16 + l16) * K1_SB + ks * 32 + quad * 8];
#pragma unroll
            for (int mt = 0; mt < 2; ++mt)
#pragma unroll
                for (int nt = 0; nt < 4; ++nt)
                    acc[mt][nt] = __builtin_amdgcn_mfma_f32_16x16x32_bf16(
                        af[mt], bfr[nt], acc[mt][nt], 0, 0, 0);
        }
    }
    // epilogue: atomic accumulate (4 chunks per element, bias pre-set by k0)
#pragma unroll
    for (int nt = 0; nt < 4; ++nt) {
        int col = wc * 64 + nt * 16 + l16;
#pragma unroll
        for (int mt = 0; mt < 2; ++mt)
#pragma unroll
            for (int r = 0; r < 4; ++r) {
                int row = wr * 32 + mt * 16 + quad * 4 + r;
                unsafeAtomicAdd(&c_all[(size_t)(m0 + row) * 128 + col], acc[mt][nt][r]);
            }
    }
}

// =====================================================================
// K2: fused query tail (seq-len 1 => softmax==1 => ctx==v exactly).
//   LN1 -> @Wv^T+bv (MFMA) -> LN2 in-register -> @Wo^T+bo (MFMA) -> normalize
// =====================================================================
#define K2_ST 136

__global__ __launch_bounds__(256) void k2_query(
    const float* __restrict__ c_all,
    const float* __restrict__ Wv, const float* __restrict__ bv,
    const float* __restrict__ Wo, const float* __restrict__ bo,
    const float* __restrict__ g1, const float* __restrict__ b1,
    const float* __restrict__ g2, const float* __restrict__ b2,
    float* __restrict__ qn)
{
    __shared__ bf16_t tT[64 * K2_ST];
    __shared__ bf16_t tW[128 * K2_ST];

    const int tid  = threadIdx.x;
    const int wid  = tid >> 6;
    const int lane = tid & 63;
    const int quad = lane >> 4;
    const int l16  = lane & 15;
    const int t0   = blockIdx.x * 64;
    const int r0   = wid * 16;

    float bvr[8], g2r[8], b2r[8], bor[8];
#pragma unroll
    for (int nt = 0; nt < 8; ++nt) {
        int col = nt * 16 + l16;
        bvr[nt] = bv[col]; g2r[nt] = g2[col]; b2r[nt] = b2[col]; bor[nt] = bo[col];
    }
    const float g1l = g1[lane], g1h = g1[64 + lane];
    const float b1l = b1[lane], b1h = b1[64 + lane];

    for (int i = 0; i < 16; ++i) {
        int row = r0 + i;
        const float* src = c_all + (size_t)(t0 + row) * 128;
        float x0 = src[lane], x1 = src[64 + lane];
        float s = x0 + x1, q = x0 * x0 + x1 * x1;
#pragma unroll
        for (int m = 1; m < 64; m <<= 1) { s += __shfl_xor(s, m); q += __shfl_xor(q, m); }
        float mean = s * (1.f / 128.f);
        float var  = q * (1.f / 128.f) - mean * mean;
        float rs   = rsqrtf(var + LN_EPS);
        tT[row * K2_ST + lane]      = (bf16_t)((x0 - mean) * rs * g1l + b1l);
        tT[row * K2_ST + 64 + lane] = (bf16_t)((x1 - mean) * rs * g1h + b1h);
    }
#pragma unroll
    for (int i = 0; i < 16; ++i) {
        int idx = i * 1024 + tid * 4;
        int r = idx >> 7, cc = idx & 127;
        float4 v = *(const float4*)(Wv + idx);
        bf16x4 pk; pk.x = (bf16_t)v.x; pk.y = (bf16_t)v.y;
                   pk.z = (bf16_t)v.z; pk.w = (bf16_t)v.w;
        *(bf16x4*)&tW[r * K2_ST + cc] = pk;
    }
    __syncthreads();

    floatx4 acc[8];
#pragma unroll
    for (int nt = 0; nt < 8; ++nt) acc[nt] = (floatx4)0.f;
#pragma unroll
    for (int ks = 0; ks < 4; ++ks) {
        bf16x8 a = *(const bf16x8*)&tT[(r0 + l16) * K2_ST + ks * 32 + quad * 8];
#pragma unroll
        for (int nt = 0; nt < 8; ++nt) {
            bf16x8 b = *(const bf16x8*)&tW[(nt * 16 + l16) * K2_ST + ks * 32 + quad * 8];
            acc[nt] = __builtin_amdgcn_mfma_f32_16x16x32_bf16(a, b, acc[nt], 0, 0, 0);
        }
    }
#pragma unroll
    for (int nt = 0; nt < 8; ++nt)
#pragma unroll
        for (int r = 0; r < 4; ++r) acc[nt][r] += bvr[nt];

#pragma unroll
    for (int r = 0; r < 4; ++r) {   // LN2 in-register (row = quad*4+r spans 8 nt x 16 lanes)
        float s = 0.f, q = 0.f;
#pragma unroll
        for (int nt = 0; nt < 8; ++nt) { float x = acc[nt][r]; s += x; q += x * x; }
#pragma unroll
        for (int m = 1; m < 16; m <<= 1) { s += __shfl_xor(s, m); q += __shfl_xor(q, m); }
        float mean = s * (1.f / 128.f);
        float var  = q * (1.f / 128.f) - mean * mean;
        float rs   = rsqrtf(var + LN_EPS);
        int row = r0 + quad * 4 + r;
#pragma unroll
        for (int nt = 0; nt < 8; ++nt) {
            float y = (acc[nt][r] - mean) * rs * g2r[nt] + b2r[nt];
            tT[row * K2_ST + nt * 16 + l16] = (bf16_t)y;
        }
    }
    __syncthreads();
#pragma unroll
    for (int i = 0; i < 16; ++i) {
        int idx = i * 1024 + tid * 4;
        int r = idx >> 7, cc = idx & 127;
        float4 v = *(const float4*)(Wo + idx);
        bf16x4 pk; pk.x = (bf16_t)v.x; pk.y = (bf16_t)v.y;
                   pk.z = (bf16_t)v.z; pk.w = (bf16_t)v.w;
        *(bf16x4*)&tW[r * K2_ST + cc] = pk;
    }
    __syncthreads();

#pragma unroll
    for (int nt = 0; nt < 8; ++nt) acc[nt] = (floatx4)0.f;
#pragma unroll
    for (int ks = 0; ks < 4; ++ks) {
        bf16x8 a = *(const bf16x8*)&tT[(r0 + l16) * K2_ST + ks * 32 + quad * 8];
#pragma unroll
        for (int nt = 0; nt < 8; ++nt) {
            bf16x8 b = *(const bf16x8*)&tW[(nt * 16 + l16) * K2_ST + ks * 32 + quad * 8];
            acc[nt] = __builtin_amdgcn_mfma_f32_16x16x32_bf16(a, b, acc[nt], 0, 0, 0);
        }
    }
#pragma unroll
    for (int r = 0; r < 4; ++r) {
        float q = 0.f;
#pragma unroll
        for (int nt = 0; nt < 8; ++nt) {
            float x = acc[nt][r] + bor[nt]; acc[nt][r] = x; q += x * x;
        }
#pragma unroll
        for (int m = 1; m < 16; m <<= 1) q += __shfl_xor(q, m);
        float inv = 1.f / fmaxf(sqrtf(q), 1e-8f);
        int row = t0 + r0 + quad * 4 + r;
#pragma unroll
        for (int nt = 0; nt < 8; ++nt)
            qn[(size_t)row * 128 + nt * 16 + l16] = acc[nt][r] * inv;
    }
}

// =====================================================================
// K3: support path, 1 task/block. R1's version read W rows per-lane
// (64 scattered cache lines per instr). Now: stage each W into LDS as
// bf16 with coalesced float4 loads, matvec from LDS.
// =====================================================================
__global__ __launch_bounds__(256) void k3_support(
    const float* __restrict__ c_all,
    const float* __restrict__ Wq, const float* __restrict__ bq,
    const float* __restrict__ Wk, const float* __restrict__ bk,
    const float* __restrict__ Wv, const float* __restrict__ bv,
    const float* __restrict__ Wo, const float* __restrict__ bo,
    const float* __restrict__ g1, const float* __restrict__ b1,
    const float* __restrict__ g2, const float* __restrict__ b2,
    float* __restrict__ pn)
{
    __shared__ float  cs[4][128];
    __shared__ bf16_t tW[128 * K2_ST];
    __shared__ float  qkv[3][4][128];
    __shared__ float  att[4][4];
    __shared__ float  ctx[4][128];

    const int tid  = threadIdx.x;
    const int wid  = tid >> 6;
    const int lane = tid & 63;
    const int task = blockIdx.x;

    { // LN1, wave per token row
        const float* src = c_all + (size_t)(16384 + task * 4 + wid) * 128;
        float x0 = src[lane], x1 = src[64 + lane];
        float s = x0 + x1, q = x0 * x0 + x1 * x1;
#pragma unroll
        for (int m = 1; m < 64; m <<= 1) { s += __shfl_xor(s, m); q += __shfl_xor(q, m); }
        float mean = s * (1.f / 128.f);
        float var  = q * (1.f / 128.f) - mean * mean;
        float rs   = rsqrtf(var + LN_EPS);
        cs[wid][lane]      = (x0 - mean) * rs * g1[lane] + b1[lane];
        cs[wid][64 + lane] = (x1 - mean) * rs * g1[64 + lane] + b1[64 + lane];
    }

    const float* Ws[3] = { Wq, Wk, Wv };
    const float* Bs[3] = { bq, bk, bv };
    for (int w = 0; w < 3; ++w) {
        __syncthreads();   // protect tW from previous phase's readers
#pragma unroll
        for (int i = 0; i < 16; ++i) {   // stage W coalesced -> bf16 LDS
            int idx = i * 1024 + tid * 4;
            int r = idx >> 7, cc = idx & 127;
            float4 v = *(const float4*)(Ws[w] + idx);
            bf16x4 pk; pk.x = (bf16_t)v.x; pk.y = (bf16_t)v.y;
                       pk.z = (bf16_t)v.z; pk.w = (bf16_t)v.w;
            *(bf16x4*)&tW[r * K2_ST + cc] = pk;
        }
        __syncthreads();
#pragma unroll
        for (int j = 0; j < 2; ++j) {    // 512 outputs, 2/thread, from LDS
            int o = tid + j * 256;
            int s = o >> 7, n = o & 127;
            const float4* c4 = (const float4*)cs[s];
            float acc = 0.f;
#pragma unroll
            for (int k8 = 0; k8 < 16; ++k8) {
                bf16x8 wv = *(const bf16x8*)&tW[n * K2_ST + k8 * 8];
                float4 a0 = c4[k8 * 2], a1 = c4[k8 * 2 + 1];
                acc += a0.x * (float)wv[0] + a0.y * (float)wv[1]
                     + a0.z * (float)wv[2] + a0.w * (float)wv[3]
                     + a1.x * (float)wv[4] + a1.y * (float)wv[5]
                     + a1.z * (float)wv[6] + a1.w * (float)wv[7];
            }
            qkv[w][s][n] = acc + Bs[w][n];
        }
    }
    __syncthreads();
    if (tid < 16) {
        int i = tid >> 2, j = tid & 3;
        const float4* qv = (const float4*)qkv[0][i];
        const float4* kv = (const float4*)qkv[1][j];
        float acc = 0.f;
#pragma unroll
        for (int k = 0; k < 32; ++k) {
            float4 a = qv[k], b = kv[k];
            acc += a.x * b.x + a.y * b.y + a.z * b.z + a.w * b.w;
        }
        att[i][j] = acc * (float)(1.0 / (11.313708498984761 + 1e-8));
    }
    __syncthreads();
    if (tid < 4) {  // exact softmax -> +1e-10 -> renorm -> clip
        float s0 = att[tid][0], s1 = att[tid][1], s2 = att[tid][2], s3 = att[tid][3];
        float m = fmaxf(fmaxf(s0, s1), fmaxf(s2, s3));
        float e0 = expf(s0 - m), e1 = expf(s1 - m), e2 = expf(s2 - m), e3 = expf(s3 - m);
        float se = e0 + e1 + e2 + e3;
        float a0 = e0 / se + 1e-10f, a1 = e1 / se + 1e-10f;
        float a2 = e2 / se + 1e-10f, a3 = e3 / se + 1e-10f;
        float t = a0 + a1 + a2 + a3;
        att[tid][0] = fminf(fmaxf(a0 / t, 1e-7f), 1.f);
        att[tid][1] = fminf(fmaxf(a1 / t, 1e-7f), 1.f);
        att[tid][2] = fminf(fmaxf(a2 / t, 1e-7f), 1.f);
        att[tid][3] = fminf(fmaxf(a3 / t, 1e-7f), 1.f);
    }
    __syncthreads();
#pragma unroll
    for (int j = 0; j < 2; ++j) {
        int o = tid + j * 256;
        int s = o >> 7, n = o & 127;
        ctx[s][n] = att[s][0] * qkv[2][0][n] + att[s][1] * qkv[2][1][n]
                  + att[s][2] * qkv[2][2][n] + att[s][3] * qkv[2][3][n];
    }
    __syncthreads();
    { // LN2 -> cs
        float x0 = ctx[wid][lane], x1 = ctx[wid][64 + lane];
        float s = x0 + x1, q = x0 * x0 + x1 * x1;
#pragma unroll
        for (int m = 1; m < 64; m <<= 1) { s += __shfl_xor(s, m); q += __shfl_xor(q, m); }
        float mean = s * (1.f / 128.f);
        float var  = q * (1.f / 128.f) - mean * mean;
        float rs   = rsqrtf(var + LN_EPS);
        cs[wid][lane]      = (x0 - mean) * rs * g2[lane] + b2[lane];
        cs[wid][64 + lane] = (x1 - mean) * rs * g2[64 + lane] + b2[64 + lane];
    }
    __syncthreads();
#pragma unroll
    for (int i = 0; i < 16; ++i) {   // stage Wo
        int idx = i * 1024 + tid * 4;
        int r = idx >> 7, cc = idx & 127;
        float4 v = *(const float4*)(Wo + idx);
        bf16x4 pk; pk.x = (bf16_t)v.x; pk.y = (bf16_t)v.y;
                   pk.z = (bf16_t)v.z; pk.w = (bf16_t)v.w;
        *(bf16x4*)&tW[r * K2_ST + cc] = pk;
    }
    __syncthreads();
#pragma unroll
    for (int j = 0; j < 2; ++j) {    // pf = ctx' @ Wo^T + bo -> ctx
        int o = tid + j * 256;
        int s = o >> 7, n = o & 127;
        const float4* c4 = (const float4*)cs[s];
        float acc = 0.f;
#pragma unroll
        for (int k8 = 0; k8 < 16; ++k8) {
            bf16x8 wv = *(const bf16x8*)&tW[n * K2_ST + k8 * 8];
            float4 a0 = c4[k8 * 2], a1 = c4[k8 * 2 + 1];
            acc += a0.x * (float)wv[0] + a0.y * (float)wv[1]
                 + a0.z * (float)wv[2] + a0.w * (float)wv[3]
                 + a1.x * (float)wv[4] + a1.y * (float)wv[5]
                 + a1.z * (float)wv[6] + a1.w * (float)wv[7];
        }
        ctx[s][n] = acc + bo[n];
    }
    __syncthreads();
    { // normalize rows
        float x0 = ctx[wid][lane], x1 = ctx[wid][64 + lane];
        float q = x0 * x0 + x1 * x1;
#pragma unroll
        for (int m = 1; m < 64; m <<= 1) q += __shfl_xor(q, m);
        float inv = 1.f / fmaxf(sqrtf(q), 1e-8f);
        float* dst = pn + (size_t)(task * 4 + wid) * 128;
        dst[lane]      = x0 * inv;
        dst[64 + lane] = x1 * inv;
    }
}

// =====================================================================
// K4: logits = 10 * qn . pn, qn tile staged through LDS (coalesced).
// =====================================================================
__global__ __launch_bounds__(256) void k4_logits(
    const float* __restrict__ qn, const float* __restrict__ pn,
    float* __restrict__ out)
{
    __shared__ float qs[64][132];
    __shared__ float ps[4][132];
    const int tid  = threadIdx.x;
    const int task = blockIdx.x;
#pragma unroll
    for (int j = 0; j < 8; ++j) {
        int i = tid + 256 * j;          // float4 index into 64x128
        int r = i >> 5, c = (i & 31) * 4;
        *(float4*)&qs[r][c] = *(const float4*)(qn + ((size_t)task * 64 + r) * 128 + c);
    }
    if (tid < 128) {
        int r = tid >> 5, c = (tid & 31) * 4;
        *(float4*)&ps[r][c] = *(const float4*)(pn + ((size_t)task * 4 + r) * 128 + c);
    }
    __syncthreads();
    const int qi = tid >> 2, cc = tid & 3;
    const float4* q4 = (const float4*)qs[qi];
    const float4* p4 = (const float4*)ps[cc];
    float acc = 0.f;
#pragma unroll
    for (int k = 0; k < 32; ++k) {
        float4 a = q4[k], b = p4[k];
        acc += a.x * b.x + a.y * b.y + a.z * b.z + a.w * b.w;
    }
    out[(size_t)task * 256 + qi * 4 + cc] = acc * 10.f;
}

// =====================================================================
extern "C" void kernel_launch(void* const* d_in, const int* in_sizes, int n_in,
                              void* d_out, int out_size, void* d_ws, size_t ws_size,
                              hipStream_t stream)
{
    const float* simg = (const float*)d_in[0];
    const float* stxt = (const float*)d_in[1];
    const float* qimg = (const float*)d_in[3];
    const float* qtxt = (const float*)d_in[4];
    const float* Wi = (const float*)d_in[5];
    const float* bi = (const float*)d_in[6];
    const float* Wt = (const float*)d_in[7];
    const float* bt = (const float*)d_in[8];
    const float* g1 = (const float*)d_in[9];
    const float* b1 = (const float*)d_in[10];
    const float* Wq = (const float*)d_in[11];
    const float* bq = (const float*)d_in[12];
    const float* Wk = (const float*)d_in[13];
    const float* bk = (const float*)d_in[14];
    const float* Wv = (const float*)d_in[15];
    const float* bv = (const float*)d_in[16];
    const float* g2 = (const float*)d_in[17];
    const float* b2 = (const float*)d_in[18];
    const float* Wo = (const float*)d_in[19];
    const float* bo = (const float*)d_in[20];
    float* out = (float*)d_out;

    float* c_all = (float*)d_ws;                       // 17408 x 128
    float* qn    = c_all + (size_t)17408 * 128;        // 16384 x 128
    float* pn    = qn    + (size_t)16384 * 128;        // 1024 x 128

    k0_init<<<2176, 256, 0, stream>>>(bi, bt, c_all);
    k1_gemm<<<dim3(272, 4), 256, 0, stream>>>(qimg, qtxt, simg, stxt, Wi, Wt, c_all);
    k2_query<<<256, 256, 0, stream>>>(c_all, Wv, bv, Wo, bo, g1, b1, g2, b2, qn);
    k3_support<<<256, 256, 0, stream>>>(c_all, Wq, bq, Wk, bk, Wv, bv, Wo, bo,
                                        g1, b1, g2, b2, pn);
    k4_logits<<<256, 256, 0, stream>>>(qn, pn, out);
}

// Round 3
// 325.614 us; speedup vs baseline: 1.1816x; 1.1816x over previous
//
#include <hip/hip_runtime.h>

typedef __bf16 bf16_t;
typedef __attribute__((ext_vector_type(4))) __bf16 bf16x4;
typedef __attribute__((ext_vector_type(8))) __bf16 bf16x8;
typedef __attribute__((ext_vector_type(4))) float floatx4;

#define LN_EPS 1e-5f

// async global->LDS, 16B per lane: LDS dest = wave-uniform base + lane*16
__device__ __forceinline__ void dma16(const void* g, void* l) {
    __builtin_amdgcn_global_load_lds(
        (const __attribute__((address_space(1))) void*)g,
        (__attribute__((address_space(3))) void*)l, 16, 0, 0);
}

// =====================================================================
// K0: init c_all with bias; convert Wq/Wk/Wv/Wo -> bf16 workspace copies.
// blocks 0..2175: c_all (557056 float4). blocks 2176..2239: weights
// (4 x 16384 floats = 16384 float4, 256 per block).
// =====================================================================
__global__ __launch_bounds__(256) void k0_prep(
    const float* __restrict__ bi, const float* __restrict__ bt,
    const float* __restrict__ Wq, const float* __restrict__ Wk,
    const float* __restrict__ Wv, const float* __restrict__ Wo,
    float* __restrict__ c_all, bf16_t* __restrict__ wbf)
{
    const int b = blockIdx.x;
    if (b < 2176) {
        int i = b * 256 + threadIdx.x;
        int c4 = i & 31;
        float4 a = ((const float4*)bi)[c4];
        float4 bb = ((const float4*)bt)[c4];
        float4 v; v.x = a.x + bb.x; v.y = a.y + bb.y; v.z = a.z + bb.z; v.w = a.w + bb.w;
        ((float4*)c_all)[i] = v;
    } else {
        int i4 = (b - 2176) * 256 + threadIdx.x;   // float4 index, 0..16383
        int which = i4 >> 12;                       // 4096 float4 per matrix
        int off4  = i4 & 4095;
        const float* W = (which == 0) ? Wq : (which == 1) ? Wk : (which == 2) ? Wv : Wo;
        float4 v = ((const float4*)W)[off4];
        bf16x4 pk; pk.x = (bf16_t)v.x; pk.y = (bf16_t)v.y;
                   pk.z = (bf16_t)v.z; pk.w = (bf16_t)v.w;
        *(bf16x4*)&wbf[which * 16384 + off4 * 4] = pk;
    }
}

// =====================================================================
// K1: c_all += [img|txt] @ [Wi|Wt]^T  (split-K x4, atomic epilogue).
// BM=64, BN=128, BK=32. fp32 tiles staged via global_load_lds (DMA,
// no VGPR round trip). LDS layout: row-major, 16B chunks XOR-swizzled
// (pos = chunk ^ (row&7)) so fragment ds_read_b128 are conflict-free
// while DMA keeps full 128B/row global coalescing. 24 KB LDS -> 6 blk/CU.
// =====================================================================
__global__ __launch_bounds__(256, 4) void k1_gemm(
    const float* __restrict__ qimg, const float* __restrict__ qtxt,
    const float* __restrict__ simg, const float* __restrict__ stxt,
    const float* __restrict__ Wi,   const float* __restrict__ Wt,
    float* __restrict__ c_all)
{
    __shared__ float lA[64 * 32];     // 8 KB
    __shared__ float lB[128 * 32];    // 16 KB

    const int tid  = threadIdx.x;
    const int m0   = blockIdx.x * 64;
    const int chnk = blockIdx.y;
    const bool isq = (m0 < 16384);
    const int rb   = isq ? m0 : (m0 - 16384);
    const float* Aimg = isq ? qimg : simg;
    const float* Atxt = isq ? qtxt : stxt;

    const int wid  = tid >> 6;
    const int lane = tid & 63;
    const int quad = lane >> 4;
    const int l16  = lane & 15;
    const int wr   = wid >> 1;
    const int wc   = wid & 1;

    // DMA lane decomposition: 1 instr = 8 rows x 8 chunk-positions
    const int jr = lane >> 3;                 // row offset 0..7
    const int cA = (lane & 7) ^ jr;           // swizzled source chunk

    floatx4 acc[2][4];
#pragma unroll
    for (int i = 0; i < 2; ++i)
#pragma unroll
        for (int j = 0; j < 4; ++j) acc[i][j] = (floatx4)0.f;

    for (int s = 0; s < 22; ++s) {
        const int k0 = chnk * 704 + s * 32;   // 32 | 2048 => never straddles img/txt
        const float* abase; const float* bbase; size_t lda, ldb;
        if (k0 < 2048) {
            abase = Aimg + (size_t)rb * 2048 + k0; lda = 2048;
            bbase = Wi + k0;                        ldb = 2048;
        } else {
            abase = Atxt + (size_t)rb * 768 + (k0 - 2048); lda = 768;
            bbase = Wt + (k0 - 2048);                       ldb = 768;
        }
        __syncthreads();   // prev slab's fragment reads done
#pragma unroll
        for (int ii = 0; ii < 2; ++ii) {      // A: rows 8i..8i+7
            int i = 2 * wid + ii;
            dma16(abase + (size_t)(8 * i + jr) * lda + (cA << 2),
                  (char*)lA + i * 1024);
        }
#pragma unroll
        for (int ii = 0; ii < 4; ++ii) {      // B: rows 8i..8i+7
            int i = 4 * wid + ii;
            dma16(bbase + (size_t)(8 * i + jr) * ldb + (cA << 2),
                  (char*)lB + i * 1024);
        }
        __syncthreads();   // vmcnt(0) drains the DMA queue

        const int x7 = l16 & 7;
        bf16x8 af[2], bfr[4];
#pragma unroll
        for (int mt = 0; mt < 2; ++mt) {
            int R = wr * 32 + mt * 16 + l16;
            float4 f0 = *(const float4*)&lA[R * 32 + (((2 * quad)     ^ x7) << 2)];
            float4 f1 = *(const float4*)&lA[R * 32 + (((2 * quad + 1) ^ x7) << 2)];
            bf16x8 a;
            a[0] = (bf16_t)f0.x; a[1] = (bf16_t)f0.y; a[2] = (bf16_t)f0.z; a[3] = (bf16_t)f0.w;
            a[4] = (bf16_t)f1.x; a[5] = (bf16_t)f1.y; a[6] = (bf16_t)f1.z; a[7] = (bf16_t)f1.w;
            af[mt] = a;
        }
#pragma unroll
        for (int nt = 0; nt < 4; ++nt) {
            int R = wc * 64 + nt * 16 + l16;
            float4 f0 = *(const float4*)&lB[R * 32 + (((2 * quad)     ^ x7) << 2)];
            float4 f1 = *(const float4*)&lB[R * 32 + (((2 * quad + 1) ^ x7) << 2)];
            bf16x8 b;
            b[0] = (bf16_t)f0.x; b[1] = (bf16_t)f0.y; b[2] = (bf16_t)f0.z; b[3] = (bf16_t)f0.w;
            b[4] = (bf16_t)f1.x; b[5] = (bf16_t)f1.y; b[6] = (bf16_t)f1.z; b[7] = (bf16_t)f1.w;
            bfr[nt] = b;
        }
#pragma unroll
        for (int mt = 0; mt < 2; ++mt)
#pragma unroll
            for (int nt = 0; nt < 4; ++nt)
                acc[mt][nt] = __builtin_amdgcn_mfma_f32_16x16x32_bf16(
                    af[mt], bfr[nt], acc[mt][nt], 0, 0, 0);
    }
#pragma unroll
    for (int nt = 0; nt < 4; ++nt) {
        int col = wc * 64 + nt * 16 + l16;
#pragma unroll
        for (int mt = 0; mt < 2; ++mt)
#pragma unroll
            for (int r = 0; r < 4; ++r) {
                int row = wr * 32 + mt * 16 + quad * 4 + r;
                unsafeAtomicAdd(&c_all[(size_t)(m0 + row) * 128 + col], acc[mt][nt][r]);
            }
    }
}

// =====================================================================
// K2: fused query tail + logits. 1 block = 1 task (64 query tokens).
//   LN1 -> @Wv^T+bv (MFMA) -> LN2 in-reg -> @Wo^T+bo (MFMA) -> normalize
//   -> logits vs pn[task] (k4 merged here; qn never materialized).
// Weights are pre-converted bf16, DMA-staged with 16B XOR swizzle
// (pos = chunk ^ (row&15), 16 chunks/row of 128 bf16).
// =====================================================================
#define K2_ST 136

__global__ __launch_bounds__(256) void k2_query(
    const float* __restrict__ c_all, const bf16_t* __restrict__ wbf,
    const float* __restrict__ bv, const float* __restrict__ bo,
    const float* __restrict__ g1, const float* __restrict__ b1,
    const float* __restrict__ g2, const float* __restrict__ b2,
    const float* __restrict__ pn, float* __restrict__ out)
{
    __shared__ bf16_t tT[64 * K2_ST];   // 17.4 KB
    __shared__ bf16_t tW[128 * 128];    // 32 KB (raw, DMA target)
    __shared__ float  pl[4][132];       // prototypes of this task

    const int tid  = threadIdx.x;
    const int wid  = tid >> 6;
    const int lane = tid & 63;
    const int quad = lane >> 4;
    const int l16  = lane & 15;
    const int task = blockIdx.x;
    const int t0   = task * 64;
    const int r0   = wid * 16;

    const bf16_t* Wvb = wbf + 2 * 16384;
    const bf16_t* Wob = wbf + 3 * 16384;

    // ---- stage Wv (DMA): 32 instrs, 8 per wave; instr = 4 rows x 16 pos
    const int jr4 = lane >> 4;          // row offset 0..3
    const int jp  = lane & 15;          // position 0..15
#pragma unroll
    for (int ii = 0; ii < 8; ++ii) {
        int i = 8 * wid + ii;
        int row = 4 * i + jr4;
        int c = jp ^ (row & 15);
        dma16(Wvb + row * 128 + c * 8, (char*)tW + i * 1024);
    }
    if (tid < 128) {                    // prototypes (written by k3)
        int r = tid >> 5, c4 = tid & 31;
        *(float4*)&pl[r][c4 * 4] = *(const float4*)(pn + ((size_t)task * 4 + r) * 128 + c4 * 4);
    }

    // ---- per-lane constants
    float bvr[8], g2r[8], b2r[8], bor[8];
#pragma unroll
    for (int nt = 0; nt < 8; ++nt) {
        int col = nt * 16 + l16;
        bvr[nt] = bv[col]; g2r[nt] = g2[col]; b2r[nt] = b2[col]; bor[nt] = bo[col];
    }

    // ---- LN1: 8 rows in parallel per wave (8 lanes per row), 2 passes
    const int g8 = lane >> 3;           // row within pass
    const int s8 = lane & 7;            // 16-float segment
    float g1a[16], b1a[16];
#pragma unroll
    for (int mm = 0; mm < 4; ++mm) {
        *(float4*)&g1a[mm * 4] = ((const float4*)(g1 + s8 * 16))[mm];
        *(float4*)&b1a[mm * 4] = ((const float4*)(b1 + s8 * 16))[mm];
    }
#pragma unroll
    for (int p = 0; p < 2; ++p) {
        int rloc = r0 + p * 8 + g8;
        const float* src = c_all + (size_t)(t0 + rloc) * 128 + s8 * 16;
        float v[16];
#pragma unroll
        for (int mm = 0; mm < 4; ++mm) *(float4*)&v[mm * 4] = ((const float4*)src)[mm];
        float s = 0.f, q = 0.f;
#pragma unroll
        for (int m = 0; m < 16; ++m) { s += v[m]; q += v[m] * v[m]; }
#pragma unroll
        for (int m = 1; m < 8; m <<= 1) { s += __shfl_xor(s, m); q += __shfl_xor(q, m); }
        float mean = s * (1.f / 128.f);
        float var  = q * (1.f / 128.f) - mean * mean;
        float rs   = rsqrtf(var + LN_EPS);
        bf16x8 o0, o1;
#pragma unroll
        for (int m = 0; m < 8; ++m)  o0[m] = (bf16_t)((v[m] - mean) * rs * g1a[m] + b1a[m]);
#pragma unroll
        for (int m = 0; m < 8; ++m)  o1[m] = (bf16_t)((v[8 + m] - mean) * rs * g1a[8 + m] + b1a[8 + m]);
        *(bf16x8*)&tT[rloc * K2_ST + s8 * 16]     = o0;
        *(bf16x8*)&tT[rloc * K2_ST + s8 * 16 + 8] = o1;
    }
    __syncthreads();   // drains DMA (Wv, pl) + LN writes

    // ---- MFMA1: v = LN1(c) @ Wv^T + bv
    floatx4 acc[8];
#pragma unroll
    for (int nt = 0; nt < 8; ++nt) acc[nt] = (floatx4)0.f;
#pragma unroll
    for (int ks = 0; ks < 4; ++ks) {
        bf16x8 a = *(const bf16x8*)&tT[(r0 + l16) * K2_ST + ks * 32 + quad * 8];
#pragma unroll
        for (int nt = 0; nt < 8; ++nt) {
            bf16x8 b = *(const bf16x8*)&tW[(nt * 16 + l16) * 128 + (((ks * 4 + quad) ^ l16) << 3)];
            acc[nt] = __builtin_amdgcn_mfma_f32_16x16x32_bf16(a, b, acc[nt], 0, 0, 0);
        }
    }
#pragma unroll
    for (int nt = 0; nt < 8; ++nt)
#pragma unroll
        for (int r = 0; r < 4; ++r) acc[nt][r] += bvr[nt];

    // ---- LN2 in-register -> tT
#pragma unroll
    for (int r = 0; r < 4; ++r) {
        float s = 0.f, q = 0.f;
#pragma unroll
        for (int nt = 0; nt < 8; ++nt) { float x = acc[nt][r]; s += x; q += x * x; }
#pragma unroll
        for (int m = 1; m < 16; m <<= 1) { s += __shfl_xor(s, m); q += __shfl_xor(q, m); }
        float mean = s * (1.f / 128.f);
        float var  = q * (1.f / 128.f) - mean * mean;
        float rs   = rsqrtf(var + LN_EPS);
        int row = r0 + quad * 4 + r;
#pragma unroll
        for (int nt = 0; nt < 8; ++nt)
            tT[row * K2_ST + nt * 16 + l16] = (bf16_t)((acc[nt][r] - mean) * rs * g2r[nt] + b2r[nt]);
    }
    __syncthreads();   // all waves done reading Wv
#pragma unroll
    for (int ii = 0; ii < 8; ++ii) {    // stage Wo
        int i = 8 * wid + ii;
        int row = 4 * i + jr4;
        int c = jp ^ (row & 15);
        dma16(Wob + row * 128 + c * 8, (char*)tW + i * 1024);
    }
    __syncthreads();   // drain

    // ---- MFMA2: qf = LN2(v) @ Wo^T + bo
#pragma unroll
    for (int nt = 0; nt < 8; ++nt) acc[nt] = (floatx4)0.f;
#pragma unroll
    for (int ks = 0; ks < 4; ++ks) {
        bf16x8 a = *(const bf16x8*)&tT[(r0 + l16) * K2_ST + ks * 32 + quad * 8];
#pragma unroll
        for (int nt = 0; nt < 8; ++nt) {
            bf16x8 b = *(const bf16x8*)&tW[(nt * 16 + l16) * 128 + (((ks * 4 + quad) ^ l16) << 3)];
            acc[nt] = __builtin_amdgcn_mfma_f32_16x16x32_bf16(a, b, acc[nt], 0, 0, 0);
        }
    }

    // ---- normalize + logits (k4 fused)
#pragma unroll
    for (int r = 0; r < 4; ++r) {
        float st[8]; float q = 0.f;
#pragma unroll
        for (int nt = 0; nt < 8; ++nt) {
            float x = acc[nt][r] + bor[nt]; st[nt] = x; q += x * x;
        }
#pragma unroll
        for (int m = 1; m < 16; m <<= 1) q += __shfl_xor(q, m);
        float inv = 1.f / fmaxf(sqrtf(q), 1e-8f);
        float d0 = 0.f, d1 = 0.f, d2 = 0.f, d3 = 0.f;
#pragma unroll
        for (int nt = 0; nt < 8; ++nt) {
            float xn = st[nt] * inv;
            int col = nt * 16 + l16;
            d0 += xn * pl[0][col]; d1 += xn * pl[1][col];
            d2 += xn * pl[2][col]; d3 += xn * pl[3][col];
        }
#pragma unroll
        for (int m = 1; m < 16; m <<= 1) {
            d0 += __shfl_xor(d0, m); d1 += __shfl_xor(d1, m);
            d2 += __shfl_xor(d2, m); d3 += __shfl_xor(d3, m);
        }
        if (l16 == 0) {
            int qi = r0 + quad * 4 + r;
            float* o = out + (size_t)task * 256 + qi * 4;
            o[0] = d0 * 10.f; o[1] = d1 * 10.f; o[2] = d2 * 10.f; o[3] = d3 * 10.f;
        }
    }
}

// =====================================================================
// K3: support path, 1 task/block, 4 waves. Weights: pre-converted bf16,
// DMA-staged one at a time into a 32KB buffer (same swizzle as k2).
// =====================================================================
__global__ __launch_bounds__(256) void k3_support(
    const float* __restrict__ c_all, const bf16_t* __restrict__ wbf,
    const float* __restrict__ bq, const float* __restrict__ bk,
    const float* __restrict__ bv, const float* __restrict__ bo,
    const float* __restrict__ g1, const float* __restrict__ b1,
    const float* __restrict__ g2, const float* __restrict__ b2,
    float* __restrict__ pn)
{
    __shared__ float  cs[4][128];
    __shared__ bf16_t tW[128 * 128];
    __shared__ float  qkv[3][4][128];
    __shared__ float  att[4][4];
    __shared__ float  ctx[4][128];

    const int tid  = threadIdx.x;
    const int wid  = tid >> 6;
    const int lane = tid & 63;
    const int task = blockIdx.x;
    const int jr4  = lane >> 4;
    const int jp   = lane & 15;

    { // LN1, wave per token row
        const float* src = c_all + (size_t)(16384 + task * 4 + wid) * 128;
        float x0 = src[lane], x1 = src[64 + lane];
        float s = x0 + x1, q = x0 * x0 + x1 * x1;
#pragma unroll
        for (int m = 1; m < 64; m <<= 1) { s += __shfl_xor(s, m); q += __shfl_xor(q, m); }
        float mean = s * (1.f / 128.f);
        float var  = q * (1.f / 128.f) - mean * mean;
        float rs   = rsqrtf(var + LN_EPS);
        cs[wid][lane]      = (x0 - mean) * rs * g1[lane] + b1[lane];
        cs[wid][64 + lane] = (x1 - mean) * rs * g1[64 + lane] + b1[64 + lane];
    }

    const float* Bs[3] = { bq, bk, bv };
    for (int w = 0; w < 3; ++w) {
        __syncthreads();   // tW free (and cs visible at w=0)
#pragma unroll
        for (int ii = 0; ii < 8; ++ii) {
            int i = 8 * wid + ii;
            int row = 4 * i + jr4;
            int c = jp ^ (row & 15);
            dma16(wbf + w * 16384 + row * 128 + c * 8, (char*)tW + i * 1024);
        }
        __syncthreads();   // drain DMA
#pragma unroll
        for (int j = 0; j < 2; ++j) {
            int o = tid + j * 256;
            int s = o >> 7, n = o & 127;
            const float4* c4 = (const float4*)cs[s];
            float acc = 0.f;
#pragma unroll
            for (int c = 0; c < 16; ++c) {
                bf16x8 wv = *(const bf16x8*)&tW[n * 128 + ((c ^ (n & 15)) << 3)];
                float4 a0 = c4[c * 2], a1 = c4[c * 2 + 1];
                acc += a0.x * (float)wv[0] + a0.y * (float)wv[1]
                     + a0.z * (float)wv[2] + a0.w * (float)wv[3]
                     + a1.x * (float)wv[4] + a1.y * (float)wv[5]
                     + a1.z * (float)wv[6] + a1.w * (float)wv[7];
            }
            qkv[w][s][n] = acc + Bs[w][n];
        }
    }
    __syncthreads();
    if (tid < 16) {
        int i = tid >> 2, j = tid & 3;
        const float4* qv = (const float4*)qkv[0][i];
        const float4* kv = (const float4*)qkv[1][j];
        float acc = 0.f;
#pragma unroll
        for (int k = 0; k < 32; ++k) {
            float4 a = qv[k], b = kv[k];
            acc += a.x * b.x + a.y * b.y + a.z * b.z + a.w * b.w;
        }
        att[i][j] = acc * (float)(1.0 / (11.313708498984761 + 1e-8));
    }
    __syncthreads();
    if (tid < 4) {  // exact softmax -> +1e-10 -> renorm -> clip
        float s0 = att[tid][0], s1 = att[tid][1], s2 = att[tid][2], s3 = att[tid][3];
        float m = fmaxf(fmaxf(s0, s1), fmaxf(s2, s3));
        float e0 = expf(s0 - m), e1 = expf(s1 - m), e2 = expf(s2 - m), e3 = expf(s3 - m);
        float se = e0 + e1 + e2 + e3;
        float a0 = e0 / se + 1e-10f, a1 = e1 / se + 1e-10f;
        float a2 = e2 / se + 1e-10f, a3 = e3 / se + 1e-10f;
        float t = a0 + a1 + a2 + a3;
        att[tid][0] = fminf(fmaxf(a0 / t, 1e-7f), 1.f);
        att[tid][1] = fminf(fmaxf(a1 / t, 1e-7f), 1.f);
        att[tid][2] = fminf(fmaxf(a2 / t, 1e-7f), 1.f);
        att[tid][3] = fminf(fmaxf(a3 / t, 1e-7f), 1.f);
    }
    __syncthreads();
#pragma unroll
    for (int j = 0; j < 2; ++j) {
        int o = tid + j * 256;
        int s = o >> 7, n = o & 127;
        ctx[s][n] = att[s][0] * qkv[2][0][n] + att[s][1] * qkv[2][1][n]
                  + att[s][2] * qkv[2][2][n] + att[s][3] * qkv[2][3][n];
    }
    __syncthreads();
    { // LN2 -> cs
        float x0 = ctx[wid][lane], x1 = ctx[wid][64 + lane];
        float s = x0 + x1, q = x0 * x0 + x1 * x1;
#pragma unroll
        for (int m = 1; m < 64; m <<= 1) { s += __shfl_xor(s, m); q += __shfl_xor(q, m); }
        float mean = s * (1.f / 128.f);
        float var  = q * (1.f / 128.f) - mean * mean;
        float rs   = rsqrtf(var + LN_EPS);
        cs[wid][lane]      = (x0 - mean) * rs * g2[lane] + b2[lane];
        cs[wid][64 + lane] = (x1 - mean) * rs * g2[64 + lane] + b2[64 + lane];
    }
    __syncthreads();
#pragma unroll
    for (int ii = 0; ii < 8; ++ii) {    // stage Wo
        int i = 8 * wid + ii;
        int row = 4 * i + jr4;
        int c = jp ^ (row & 15);
        dma16(wbf + 3 * 16384 + row * 128 + c * 8, (char*)tW + i * 1024);
    }
    __syncthreads();
#pragma unroll
    for (int j = 0; j < 2; ++j) {       // pf = LN2 @ Wo^T + bo -> ctx
        int o = tid + j * 256;
        int s = o >> 7, n = o & 127;
        const float4* c4 = (const float4*)cs[s];
        float acc = 0.f;
#pragma unroll
        for (int c = 0; c < 16; ++c) {
            bf16x8 wv = *(const bf16x8*)&tW[n * 128 + ((c ^ (n & 15)) << 3)];
            float4 a0 = c4[c * 2], a1 = c4[c * 2 + 1];
            acc += a0.x * (float)wv[0] + a0.y * (float)wv[1]
                 + a0.z * (float)wv[2] + a0.w * (float)wv[3]
                 + a1.x * (float)wv[4] + a1.y * (float)wv[5]
                 + a1.z * (float)wv[6] + a1.w * (float)wv[7];
        }
        ctx[s][n] = acc + bo[n];
    }
    __syncthreads();
    { // normalize rows -> pn
        float x0 = ctx[wid][lane], x1 = ctx[wid][64 + lane];
        float q = x0 * x0 + x1 * x1;
#pragma unroll
        for (int m = 1; m < 64; m <<= 1) q += __shfl_xor(q, m);
        float inv = 1.f / fmaxf(sqrtf(q), 1e-8f);
        float* dst = pn + (size_t)(task * 4 + wid) * 128;
        dst[lane]      = x0 * inv;
        dst[64 + lane] = x1 * inv;
    }
}

// =====================================================================
extern "C" void kernel_launch(void* const* d_in, const int* in_sizes, int n_in,
                              void* d_out, int out_size, void* d_ws, size_t ws_size,
                              hipStream_t stream)
{
    const float* simg = (const float*)d_in[0];
    const float* stxt = (const float*)d_in[1];
    const float* qimg = (const float*)d_in[3];
    const float* qtxt = (const float*)d_in[4];
    const float* Wi = (const float*)d_in[5];
    const float* bi = (const float*)d_in[6];
    const float* Wt = (const float*)d_in[7];
    const float* bt = (const float*)d_in[8];
    const float* g1 = (const float*)d_in[9];
    const float* b1 = (const float*)d_in[10];
    const float* Wq = (const float*)d_in[11];
    const float* bq = (const float*)d_in[12];
    const float* Wk = (const float*)d_in[13];
    const float* bk = (const float*)d_in[14];
    const float* Wv = (const float*)d_in[15];
    const float* bv = (const float*)d_in[16];
    const float* g2 = (const float*)d_in[17];
    const float* b2 = (const float*)d_in[18];
    const float* Wo = (const float*)d_in[19];
    const float* bo = (const float*)d_in[20];
    float* out = (float*)d_out;

    float*  c_all = (float*)d_ws;                         // 17408 x 128
    float*  pn    = c_all + (size_t)17408 * 128;          // 1024 x 128
    bf16_t* wbf   = (bf16_t*)(pn + (size_t)1024 * 128);   // 4 x 16384 bf16

    k0_prep<<<2240, 256, 0, stream>>>(bi, bt, Wq, Wk, Wv, Wo, c_all, wbf);
    k1_gemm<<<dim3(272, 4), 256, 0, stream>>>(qimg, qtxt, simg, stxt, Wi, Wt, c_all);
    k3_support<<<256, 256, 0, stream>>>(c_all, wbf, bq, bk, bv, bo, g1, b1, g2, b2, pn);
    k2_query<<<256, 256, 0, stream>>>(c_all, wbf, bv, bo, g1, b1, g2, b2, pn, out);
}